// Round 7
// baseline (228.361 us; speedup 1.0000x reference)
//
#include <hip/hip_runtime.h>
#include <hip/hip_bf16.h>

// Problem constants: B=1, N=128, L=256, D=256, P=128, H=8, DH=32
// Established: fp32 inputs, fp32 output; bf16-rounded ref, threshold 0.0289.
#define NN 128
#define LL 256
#define DD 256
#define PP 128
#define HH 8
#define DHH 32

typedef __bf16 bf16x8 __attribute__((ext_vector_type(8)));
typedef short s16x4 __attribute__((ext_vector_type(4)));
typedef short s16x8 __attribute__((ext_vector_type(8)));
typedef float f32x4 __attribute__((ext_vector_type(4)));
typedef unsigned int u32x2 __attribute__((ext_vector_type(2)));

// scale * log2(e), folded into Q at the producer (round 7).
#define QSCALE_CS 0.2550889091487754f  // 0.17677669529663687 * 1.4426950408889634

// k' permutation: within each 64-block, swap bits[5:4] (nj) with bits[3:2]
// (quad) so that a lane's MFMA-fragment elements become CONTIGUOUS 16
// values. Self-inverse. Applied at the producers for expb, vb, msk.
__device__ __forceinline__ int permk(int k) {
  return (k & 0xC3) | ((k & 0x30) >> 2) | ((k & 0x0C) << 2);
}

// async global->LDS, 16B per lane (dest = wave-uniform base + lane*16)
__device__ __forceinline__ void gload_lds16(const void* g, void* l) {
  __builtin_amdgcn_global_load_lds(
      (const __attribute__((address_space(1))) void*)g,
      (__attribute__((address_space(3))) void*)l, 16, 0, 0);
}

// ---------------------------------------------------------------------------
// fp32 -> bf16 bulk convert
// ---------------------------------------------------------------------------
__global__ __launch_bounds__(256) void cvt_bf16(
    const float* __restrict__ src, __hip_bfloat16* __restrict__ dst, int n) {
  for (int i = (blockIdx.x * 256 + threadIdx.x) * 4; i < n; i += gridDim.x * 1024) {
    float4 v = *(const float4*)(src + i);
    ushort4 o;
    o.x = __bfloat16_as_ushort(__float2bfloat16(v.x));
    o.y = __bfloat16_as_ushort(__float2bfloat16(v.y));
    o.z = __bfloat16_as_ushort(__float2bfloat16(v.z));
    o.w = __bfloat16_as_ushort(__float2bfloat16(v.w));
    *(ushort4*)(dst + i) = o;
  }
}

// ---------------------------------------------------------------------------
// transpose + convert: src [K][N] fp32 -> dst [N][K] bf16
// ---------------------------------------------------------------------------
__global__ __launch_bounds__(256) void transpose_cvt(
    const float* __restrict__ src, __hip_bfloat16* __restrict__ dst,
    int K, int N) {
  __shared__ float t[32][33];
  int n0 = blockIdx.x * 32, k0 = blockIdx.y * 32;
  int tx = threadIdx.x & 31, ty = threadIdx.x >> 5;
  for (int i = 0; i < 4; ++i) {
    int ky = ty + i * 8;
    t[ky][tx] = src[(size_t)(k0 + ky) * N + n0 + tx];
  }
  __syncthreads();
  for (int i = 0; i < 4; ++i) {
    int ny = ty + i * 8;
    dst[(size_t)(n0 + ny) * K + k0 + tx] = __float2bfloat16(t[tx][ny]);
  }
}

// ---------------------------------------------------------------------------
// mask normalization -> bf16 1.0/0.0 at k'-PERMUTED index (round 7: bf16 so
// it can feed the lsum mask-MFMA A-fragment directly).
// ---------------------------------------------------------------------------
#define MODE_I32 0
#define MODE_I8 1
#define MODE_BF16 2
#define MODE_F32 3

__global__ __launch_bounds__(256) void mask_expand(
    const unsigned char* __restrict__ mraw, __hip_bfloat16* __restrict__ mout) {
  __shared__ int s_or1, s_or2, s_or3, s_max, s_mode;
  int tid = threadIdx.x;
  if (tid == 0) { s_or1 = 0; s_or2 = 0; s_or3 = 0; s_max = 0; }
  __syncthreads();
  int or1 = 0, or2 = 0, or3 = 0, mx = 0;
  for (int j = tid; j < 4096; j += 256) {
    int b = mraw[j];
    mx = mx > b ? mx : b;
    int r = j & 3;
    if (r == 1) or1 |= b;
    else if (r == 2) or2 |= b;
    else if (r == 3) or3 |= b;
  }
  atomicOr(&s_or1, or1); atomicOr(&s_or2, or2); atomicOr(&s_or3, or3);
  atomicMax(&s_max, mx);
  __syncthreads();
  if (tid == 0) {
    int mode;
    if (s_max <= 1) mode = ((s_or1 | s_or2 | s_or3) == 0) ? MODE_I32 : MODE_I8;
    else            mode = (s_or1 != 0) ? MODE_BF16 : MODE_F32;
    s_mode = mode;
  }
  __syncthreads();
  int mode = s_mode;
  int i0 = blockIdx.x * 1024;
  for (int i = i0 + tid; i < i0 + 1024; i += 256) {
    int v;
    if (mode == MODE_I32)       v = ((const int*)mraw)[i] != 0;
    else if (mode == MODE_I8)   v = mraw[i] != 0;
    else if (mode == MODE_BF16) v = ((const unsigned short*)mraw)[i] != 0;
    else                        v = ((const unsigned int*)mraw)[i] != 0;
    mout[(i & ~255) | permk(i & 255)] = __float2bfloat16(v ? 1.f : 0.f);
  }
}

// ---------------------------------------------------------------------------
// MFMA GEMM pipeline (A [M][256] bf16, Bt [N][256] bf16 = B^T).
// 128x128 tile, BK=32, 4 waves of 64x64, SWAPPED mfma (C^T fragments: lane
// holds 4 consecutive gcol at one grow -> wide coalesced stores).
// 2-phase LDS double-buffer; XOR-swizzle via pre-swizzled global source.
// ---------------------------------------------------------------------------
#define GSTAGE(AD, BD, KS)                                                    \
  {                                                                           \
    const int k0_ = (KS) * 32;                                                \
    gload_lds16(Aptr + ((size_t)(bm * 128 + srow)) * 256 + k0_ + scc * 8,     \
                AD + (size_t)(wv * 64) * 8);                                  \
    gload_lds16(Btptr + ((size_t)(bn * 128 + srow)) * 256 + k0_ + scc * 8,    \
                BD + (size_t)(wv * 64) * 8);                                  \
    gload_lds16(Aptr + ((size_t)(bm * 128 + 64 + srow)) * 256 + k0_ + scc * 8,\
                AD + (size_t)(wv * 64 + 256) * 8);                            \
    gload_lds16(Btptr + ((size_t)(bn * 128 + 64 + srow)) * 256 + k0_ + scc * 8,\
                BD + (size_t)(wv * 64 + 256) * 8);                            \
  }

#define GPHASE(CA, CB, NA, NB, NKS, DOSTAGE)                                  \
  {                                                                           \
    if (DOSTAGE) GSTAGE(NA, NB, NKS)                                          \
    bf16x8 af[4], bfr[4];                                                     \
    _Pragma("unroll") for (int mi = 0; mi < 4; ++mi) {                        \
      int r_ = wm + mi * 16 + lr;                                             \
      af[mi] = *(const bf16x8*)&CA[r_ * 32 + (quad ^ (r_ & 3)) * 8];          \
    }                                                                         \
    _Pragma("unroll") for (int ni = 0; ni < 4; ++ni) {                        \
      int r_ = wn + ni * 16 + lr;                                             \
      bfr[ni] = *(const bf16x8*)&CB[r_ * 32 + (quad ^ (r_ & 3)) * 8];         \
    }                                                                         \
    _Pragma("unroll") for (int mi = 0; mi < 4; ++mi)                          \
      _Pragma("unroll") for (int ni = 0; ni < 4; ++ni)                        \
        acc[mi][ni] = __builtin_amdgcn_mfma_f32_16x16x32_bf16(                \
            bfr[ni], af[mi], acc[mi][ni], 0, 0, 0);                           \
  }                                                                           \
  __syncthreads();

#define GEMM_PIPELINE(APTR_, BTPTR_)                                          \
  const __hip_bfloat16* __restrict__ Aptr = (APTR_);                          \
  const __hip_bfloat16* __restrict__ Btptr = (BTPTR_);                        \
  __shared__ __align__(16) __hip_bfloat16 As0[128 * 32], As1[128 * 32];       \
  __shared__ __align__(16) __hip_bfloat16 Bs0[128 * 32], Bs1[128 * 32];       \
  int tid = threadIdx.x;                                                      \
  int lane = tid & 63, wv = tid >> 6;                                         \
  int wm = (wv >> 1) * 64, wn = (wv & 1) * 64;                                \
  int lr = lane & 15, quad = lane >> 4;                                       \
  int bm = blockIdx.x, bn = blockIdx.y;                                       \
  int srow = tid >> 2, sslot = tid & 3;                                       \
  int scc = sslot ^ (srow & 3);                                               \
  f32x4 acc[4][4];                                                            \
  for (int i = 0; i < 4; ++i)                                                 \
    for (int j = 0; j < 4; ++j) acc[i][j] = (f32x4){0.f, 0.f, 0.f, 0.f};      \
  GSTAGE(As0, Bs0, 0)                                                         \
  __syncthreads();                                                            \
  GPHASE(As0, Bs0, As1, Bs1, 1, 1)                                            \
  GPHASE(As1, Bs1, As0, Bs0, 2, 1)                                            \
  GPHASE(As0, Bs0, As1, Bs1, 3, 1)                                            \
  GPHASE(As1, Bs1, As0, Bs0, 4, 1)                                            \
  GPHASE(As0, Bs0, As1, Bs1, 5, 1)                                            \
  GPHASE(As1, Bs1, As0, Bs0, 6, 1)                                            \
  GPHASE(As0, Bs0, As1, Bs1, 7, 1)                                            \
  GPHASE(As1, Bs1, As0, Bs0, 8, 0)

// QKV: q (pre-scaled by QSCALE_CS), k -> [n][h][l][dh];
// v (pre-MASKED) -> [n][h][dh][l'] (transposed + k'-permuted).
__global__ __launch_bounds__(256) void qkv_gemm_mfma(
    const __hip_bfloat16* __restrict__ A,
    const __hip_bfloat16* __restrict__ Bt,
    const __hip_bfloat16* __restrict__ mskb,  // [n][k'] bf16 1/0
    __hip_bfloat16* __restrict__ qb,
    __hip_bfloat16* __restrict__ kb,
    __hip_bfloat16* __restrict__ vb) {
  GEMM_PIPELINE(A, Bt)
  int t = bn >> 1;
#pragma unroll
  for (int mi = 0; mi < 4; ++mi) {
    int g = bm * 128 + wm + mi * 16 + lr;
    int n = g >> 8, l = g & 255;
    int lp = permk(l);
    float vm = (t == 2) ? __bfloat162float(mskb[n * 256 + lp]) : 1.f;
    float sc = (t == 0) ? QSCALE_CS : ((t == 2) ? vm : 1.f);
#pragma unroll
    for (int ni = 0; ni < 4; ++ni) {
      int rem = (bn * 128 + wn + ni * 16 + quad * 4) & 255;
      int h = rem >> 5, dh0 = rem & 31;
      if (t < 2) {
        ushort4 w;
        w.x = __bfloat16_as_ushort(__float2bfloat16(acc[mi][ni][0] * sc));
        w.y = __bfloat16_as_ushort(__float2bfloat16(acc[mi][ni][1] * sc));
        w.z = __bfloat16_as_ushort(__float2bfloat16(acc[mi][ni][2] * sc));
        w.w = __bfloat16_as_ushort(__float2bfloat16(acc[mi][ni][3] * sc));
        __hip_bfloat16* dst = (t == 0 ? qb : kb);
        *(ushort4*)(dst + ((size_t)((n * HH + h) * LL + l)) * DHH + dh0) = w;
      } else {
#pragma unroll
        for (int r = 0; r < 4; ++r)
          vb[((size_t)((n * HH + h) * DHH + dh0 + r)) * LL + lp] =
              __float2bfloat16(acc[mi][ni][r] * sc);
      }
    }
  }
}

__global__ __launch_bounds__(256) void out_gemm_mfma(
    const __hip_bfloat16* __restrict__ A,
    const __hip_bfloat16* __restrict__ Bt,
    const float* __restrict__ bout,
    float* __restrict__ C) {
  GEMM_PIPELINE(A, Bt)
#pragma unroll
  for (int mi = 0; mi < 4; ++mi) {
    int g = bm * 128 + wm + mi * 16 + lr;
#pragma unroll
    for (int ni = 0; ni < 4; ++ni) {
      int gcol0 = bn * 128 + wn + ni * 16 + quad * 4;
      float4 bo = *(const float4*)(bout + gcol0);
      float4 v;
      v.x = acc[mi][ni][0] + bo.x;
      v.y = acc[mi][ni][1] + bo.y;
      v.z = acc[mi][ni][2] + bo.z;
      v.w = acc[mi][ni][3] + bo.w;
      *(float4*)(C + (size_t)g * 256 + gcol0) = v;
    }
  }
}

// ---------------------------------------------------------------------------
// pair bias -> expb[h][q][k'] = exp(pair@w_pb + b_pb - 12) bf16, k'-permuted.
// ---------------------------------------------------------------------------
__global__ __launch_bounds__(256) void pair_bias_kernel(
    const float* __restrict__ pair,
    const float* __restrict__ w_pb,
    const float* __restrict__ b_pb,
    __hip_bfloat16* __restrict__ expb) {
  __shared__ float wp[128][9];
  __shared__ float rows[32][129];
  int tid = threadIdx.x;
  for (int i = 0; i < 4; ++i) {
    int e = tid + i * 256;
    wp[e >> 3][e & 7] = w_pb[e];
  }
  int row0 = blockIdx.x * 32;
  const float* src = pair + (size_t)row0 * PP;
  for (int i = 0; i < 16; ++i) {
    int e = tid + i * 256;
    int r = e >> 7, c = e & 127;
    rows[r][c] = src[r * 128 + c];
  }
  __syncthreads();
  int h = tid >> 5, rl = tid & 31;
  float acc = b_pb[h] - 12.0f;
  for (int p = 0; p < 128; ++p)
    acc += rows[rl][p] * wp[p][h];
  int row = row0 + rl;
  int i = row >> 8, j = row & 255;
  expb[((size_t)(h * LL + i)) * LL + permk(j)] = __float2bfloat16(__expf(acc));
}

// ---------------------------------------------------------------------------
// Flash-style MFMA attention: zero LDS, swapped QK^T, fixed-shift softmax,
// pre-exponentiated bf16 bias, k'-permuted layouts, issue-ordered loads.
//
// Round-7 (attn was VALU-bound: 50% VALUBusy, 10% MfmaUtil): VALU work moved
// to producers and to the idle MFMA pipe:
//  - Q pre-scaled by scale*log2e -> p = exp2(s)*em (no per-step s*cs mul)
//  - V pre-masked at producer -> no mask multiply on p for PV
//  - lsum = mask.P row-sum via ONE extra mfma_16x16x16 per nj-step with
//    A = bf16 mask fragment (MFMA pipe 90% idle); denominator uses the
//    IDENTICAL bf16 P as the numerator (ratio-error cancellation), and the
//    epilogue shuffles disappear (each lane gets the full k-sum).
// Per nj-step: ~30 -> ~18 VALU, 4 -> 5 MFMA.
// ---------------------------------------------------------------------------
__global__ __launch_bounds__(256, 2) void attn_mfma(
    const __hip_bfloat16* __restrict__ qb,
    const __hip_bfloat16* __restrict__ kb,
    const __hip_bfloat16* __restrict__ vbt,   // [n][h][dh][k'] bf16, premasked
    const __hip_bfloat16* __restrict__ expb,  // [h][q][k'] = exp(bias-12) bf16
    const __hip_bfloat16* __restrict__ maskb, // [n][k'] bf16 1/0
    __hip_bfloat16* __restrict__ ao) {
  int bx = blockIdx.x;
  int h = bx >> 7, n = bx & 127;
  int nh = n * HH + h;
  int tid = threadIdx.x, lane = tid & 63, wv = tid >> 6;
  int lr = lane & 15, quad = lane >> 4;
  int wm = wv * 64;
  size_t base = (size_t)nh * (LL * DHH);

  const __hip_bfloat16* qp = qb + base;
  const __hip_bfloat16* kp = kb + base;
  const __hip_bfloat16* vp = vbt + base;
  const __hip_bfloat16* ep = expb + (size_t)h * LL * LL;
  const __hip_bfloat16* mrow = maskb + n * LL;

  // Q fragments (row q = wm+mi*16+lr, dh = quad*8..+7); B-operand of QK^T.
  bf16x8 aq[4];
#pragma unroll
  for (int mi = 0; mi < 4; ++mi)
    aq[mi] = *(const bf16x8*)(qp + (size_t)(wm + mi * 16 + lr) * DHH + quad * 8);

  // K double-buffered (A/B tokens); V likewise (contig 16B halves a/b per no).
  bf16x8 bkA[4], bkB[4];
  s16x8 avA0a, avA0b, avA1a, avA1b;
  s16x8 avB0a, avB0b, avB1a, avB1b;
  // eb: all 4 mi of the CURRENT kt, single-buffered (2x16B per mi).
  uint4 e0a, e0b, e1a, e1b, e2a, e2b, e3a, e3b;
  // mask bf16 fragments for current kt (k'-contiguous: nj0,1 | nj2,3).
  s16x8 mb_a, mb_b;

#define LOADKT(S, KT)                                                          \
  {                                                                            \
    const int j0_ = (KT) * 64;                                                 \
    _Pragma("unroll") for (int nj = 0; nj < 4; ++nj)                           \
        bk##S[nj] =                                                            \
        *(const bf16x8*)(kp + (size_t)(j0_ + nj * 16 + lr) * DHH + quad * 8);  \
    av##S##0a = *(const s16x8*)(vp + (size_t)lr * LL + j0_ + quad * 16);       \
    av##S##0b = *(const s16x8*)(vp + (size_t)lr * LL + j0_ + quad * 16 + 8);   \
    av##S##1a = *(const s16x8*)(vp + (size_t)(16 + lr) * LL + j0_ + quad * 16);\
    av##S##1b =                                                                \
        *(const s16x8*)(vp + (size_t)(16 + lr) * LL + j0_ + quad * 16 + 8);    \
  }

#define LOADEB_ALL(KT)                                                         \
  {                                                                            \
    const int j0_ = (KT) * 64;                                                 \
    e0a = *(const uint4*)(ep + (size_t)(wm + 0 + lr) * LL + j0_ + quad * 16);  \
    e0b = *(const uint4*)(ep + (size_t)(wm + 0 + lr) * LL + j0_ + quad * 16 + 8);\
    e1a = *(const uint4*)(ep + (size_t)(wm + 16 + lr) * LL + j0_ + quad * 16); \
    e1b = *(const uint4*)(ep + (size_t)(wm + 16 + lr) * LL + j0_ + quad * 16 + 8);\
    e2a = *(const uint4*)(ep + (size_t)(wm + 32 + lr) * LL + j0_ + quad * 16); \
    e2b = *(const uint4*)(ep + (size_t)(wm + 32 + lr) * LL + j0_ + quad * 16 + 8);\
    e3a = *(const uint4*)(ep + (size_t)(wm + 48 + lr) * LL + j0_ + quad * 16); \
    e3b = *(const uint4*)(ep + (size_t)(wm + 48 + lr) * LL + j0_ + quad * 16 + 8);\
  }

#define LOADMB(KT)                                                             \
  {                                                                            \
    const int j0_ = (KT) * 64;                                                 \
    mb_a = *(const s16x8*)(mrow + j0_ + quad * 16);                            \
    mb_b = *(const s16x8*)(mrow + j0_ + quad * 16 + 8);                        \
  }

// One nj step. EX/EY = the two eb dwords for this nj, AV0/AV1 = 16B V
// fragments (no=0,1), MB = 16B mask fragment pair, LO = elem offset (0/4).
// s_ is already fully scaled (Q pre-scaled by scale*log2e).
#define NJ_STEP(C, MI, NJ, EX, EY, AV0, AV1, MB, LO)                           \
  {                                                                            \
    f32x4 s_ = __builtin_amdgcn_mfma_f32_16x16x32_bf16(                        \
        bk##C[NJ], aq[MI], (f32x4){0.f, 0.f, 0.f, 0.f}, 0, 0, 0);              \
    float em0_ = __uint_as_float((EX) << 16);                                  \
    float em1_ = __uint_as_float((EX) & 0xffff0000u);                          \
    float em2_ = __uint_as_float((EY) << 16);                                  \
    float em3_ = __uint_as_float((EY) & 0xffff0000u);                          \
    float p0_ = exp2f(s_[0]) * em0_;                                           \
    float p1_ = exp2f(s_[1]) * em1_;                                           \
    float p2_ = exp2f(s_[2]) * em2_;                                           \
    float p3_ = exp2f(s_[3]) * em3_;                                           \
    unsigned lo_ =                                                             \
        ((unsigned)__bfloat16_as_ushort(__float2bfloat16(p1_)) << 16) |        \
        (unsigned)__bfloat16_as_ushort(__float2bfloat16(p0_));                 \
    unsigned hi_ =                                                             \
        ((unsigned)__bfloat16_as_ushort(__float2bfloat16(p3_)) << 16) |        \
        (unsigned)__bfloat16_as_ushort(__float2bfloat16(p2_));                 \
    u32x2 pu_ = {lo_, hi_};                                                    \
    s16x4 pb_ = __builtin_bit_cast(s16x4, pu_);                                \
    s16x4 a0_ = __builtin_shufflevector(AV0, AV0, LO, LO + 1, LO + 2, LO + 3); \
    s16x4 a1_ = __builtin_shufflevector(AV1, AV1, LO, LO + 1, LO + 2, LO + 3); \
    s16x4 am_ = __builtin_shufflevector(MB, MB, LO, LO + 1, LO + 2, LO + 3);   \
    o_acc[MI][0] = __builtin_amdgcn_mfma_f32_16x16x16bf16_1k(                  \
        a0_, pb_, o_acc[MI][0], 0, 0, 0);                                      \
    o_acc[MI][1] = __builtin_amdgcn_mfma_f32_16x16x16bf16_1k(                  \
        a1_, pb_, o_acc[MI][1], 0, 0, 0);                                      \
    ols_ = __builtin_amdgcn_mfma_f32_16x16x16bf16_1k(am_, pb_, ols_, 0, 0, 0); \
  }

#define MI_PHASE(MI, C, EA, EB_)                                               \
  {                                                                            \
    f32x4 ols_ = (f32x4){0.f, 0.f, 0.f, 0.f};                                  \
    NJ_STEP(C, MI, 0, EA.x, EA.y, av##C##0a, av##C##1a, mb_a, 0)               \
    NJ_STEP(C, MI, 1, EA.z, EA.w, av##C##0a, av##C##1a, mb_a, 4)               \
    NJ_STEP(C, MI, 2, EB_.x, EB_.y, av##C##0b, av##C##1b, mb_b, 0)             \
    NJ_STEP(C, MI, 3, EB_.z, EB_.w, av##C##0b, av##C##1b, mb_b, 4)             \
    lsum[MI] += ols_[0];                                                       \
  }

// Issue order per kt: eb + mask (needed in ~1 phase, L2) first, then the
// NEXT kt's K/V (HBM, consumed a full kt later). Consumption is strictly in
// issue order -> compiler's counted vmcnt never drains fresh HBM loads.
#define KT_PHASE(KT, C, N, LAST)                                               \
  {                                                                            \
    LOADEB_ALL(KT)                                                             \
    LOADMB(KT)                                                                 \
    if (!(LAST)) LOADKT(N, (KT) + 1)                                           \
    MI_PHASE(0, C, e0a, e0b)                                                   \
    MI_PHASE(1, C, e1a, e1b)                                                   \
    MI_PHASE(2, C, e2a, e2b)                                                   \
    MI_PHASE(3, C, e3a, e3b)                                                   \
  }

  float lsum[4] = {0.f, 0.f, 0.f, 0.f};
  f32x4 o_acc[4][2];
#pragma unroll
  for (int mi = 0; mi < 4; ++mi)
#pragma unroll
    for (int no = 0; no < 2; ++no) o_acc[mi][no] = (f32x4){0.f, 0.f, 0.f, 0.f};

  LOADKT(A, 0)

  KT_PHASE(0, A, B, 0)
  KT_PHASE(1, B, A, 0)
  KT_PHASE(2, A, B, 0)
  KT_PHASE(3, B, A, 1)

#undef LOADKT
#undef LOADEB_ALL
#undef LOADMB
#undef NJ_STEP
#undef MI_PHASE
#undef KT_PHASE

  // epilogue: O^T tile (row dh = no*16+quad*4+r, col q = wm+mi*16+lr).
  // lsum[mi] already holds the FULL masked row-sum (mask-MFMA contracts all
  // 16 k per step) -> no cross-lane reduction needed.
#pragma unroll
  for (int mi = 0; mi < 4; ++mi) {
    float ls = lsum[mi];
    float inv = (ls > 0.f) ? 1.f / ls : 0.f;
    int q = wm + mi * 16 + lr;
#pragma unroll
    for (int no = 0; no < 2; ++no) {
      f32x4 o = o_acc[mi][no];
      ushort4 w;
      w.x = __bfloat16_as_ushort(__float2bfloat16(o[0] * inv));
      w.y = __bfloat16_as_ushort(__float2bfloat16(o[1] * inv));
      w.z = __bfloat16_as_ushort(__float2bfloat16(o[2] * inv));
      w.w = __bfloat16_as_ushort(__float2bfloat16(o[3] * inv));
      *(ushort4*)(ao + (size_t)n * (LL * DD) + (size_t)q * DD +
                  h * DHH + no * 16 + quad * 4) = w;
    }
  }
}

extern "C" void kernel_launch(void* const* d_in, const int* in_sizes, int n_in,
                              void* d_out, int out_size, void* d_ws, size_t ws_size,
                              hipStream_t stream) {
  const float* msa   = (const float*)d_in[0];
  const float* pair  = (const float*)d_in[1];
  const unsigned char* mask = (const unsigned char*)d_in[2];
  const float* w_qkv = (const float*)d_in[3];
  const float* w_pb  = (const float*)d_in[4];
  const float* b_pb  = (const float*)d_in[5];
  const float* w_out = (const float*)d_in[6];
  const float* b_out = (const float*)d_in[7];
  float* out = (float*)d_out;

  char* ws = (char*)d_ws;
  __hip_bfloat16* qb      = (__hip_bfloat16*)(ws);                 // 16 MB
  __hip_bfloat16* kb      = (__hip_bfloat16*)(ws + 16777216);      // 16 MB
  __hip_bfloat16* vb      = (__hip_bfloat16*)(ws + 33554432);      // 16 MB [n][h][dh][k'], premasked
  __hip_bfloat16* msa_c   = (__hip_bfloat16*)(ws + 50331648);      // 16 MB
  __hip_bfloat16* ao      = (__hip_bfloat16*)(ws + 50331648);      // alias (msa dead after qkv)
  __hip_bfloat16* expb    = (__hip_bfloat16*)(ws + 67108864);      // 1 MB [h][q][k'] bf16
  __hip_bfloat16* wqkv_t  = (__hip_bfloat16*)(ws + 71303168);      // 384 KB
  __hip_bfloat16* wout_t  = (__hip_bfloat16*)(ws + 71696384);      // 128 KB
  __hip_bfloat16* msk     = (__hip_bfloat16*)(ws + 71827456);      // 64 KB [n][k'] bf16

  mask_expand<<<32, 256, 0, stream>>>(mask, msk);
  cvt_bf16<<<1024, 256, 0, stream>>>(msa, msa_c, NN * LL * DD);
  transpose_cvt<<<dim3(24, 8), 256, 0, stream>>>(w_qkv, wqkv_t, 256, 768);
  transpose_cvt<<<dim3(8, 8), 256, 0, stream>>>(w_out, wout_t, 256, 256);

  qkv_gemm_mfma<<<dim3(256, 6), 256, 0, stream>>>(msa_c, wqkv_t, msk, qb, kb, vb);
  pair_bias_kernel<<<2048, 256, 0, stream>>>(pair, w_pb, b_pb, expb);
  attn_mfma<<<1024, 256, 0, stream>>>(qb, kb, vb, expb, msk, ao);
  out_gemm_mfma<<<dim3(256, 2), 256, 0, stream>>>(ao, wout_t, b_out, out);
}

// Round 8
// 213.615 us; speedup vs baseline: 1.0690x; 1.0690x over previous
//
#include <hip/hip_runtime.h>
#include <hip/hip_bf16.h>

// Problem constants: B=1, N=128, L=256, D=256, P=128, H=8, DH=32
// Established: fp32 inputs, fp32 output; bf16-rounded ref, threshold 0.0289.
#define NN 128
#define LL 256
#define DD 256
#define PP 128
#define HH 8
#define DHH 32

typedef __bf16 bf16x8 __attribute__((ext_vector_type(8)));
typedef short s16x4 __attribute__((ext_vector_type(4)));
typedef short s16x8 __attribute__((ext_vector_type(8)));
typedef float f32x4 __attribute__((ext_vector_type(4)));
typedef unsigned int u32x2 __attribute__((ext_vector_type(2)));

// k' permutation: within each 64-block, swap bits[5:4] (nj) with bits[3:2]
// (quad) so that a lane's MFMA-fragment elements become CONTIGUOUS 16
// values. Self-inverse. Applied at the producers for expb, vb, msk.
__device__ __forceinline__ int permk(int k) {
  return (k & 0xC3) | ((k & 0x30) >> 2) | ((k & 0x0C) << 2);
}

// async global->LDS, 16B per lane (dest = wave-uniform base + lane*16)
__device__ __forceinline__ void gload_lds16(const void* g, void* l) {
  __builtin_amdgcn_global_load_lds(
      (const __attribute__((address_space(1))) void*)g,
      (__attribute__((address_space(3))) void*)l, 16, 0, 0);
}

// ---------------------------------------------------------------------------
// FUSED prep kernel (round 8: launch-gap reduction, 8 -> 4 dispatches).
// Block ranges: [0,1024) cvt msa->bf16; [1024,1056) mask normalize;
// [1056,1248) transpose w_qkv; [1248,1312) transpose w_out.
// All four are independent; each block runs exactly one branch uniformly.
// ---------------------------------------------------------------------------
#define MODE_I32 0
#define MODE_I8 1
#define MODE_BF16 2
#define MODE_F32 3

__device__ __forceinline__ void transpose_cvt_body(
    const float* __restrict__ src, __hip_bfloat16* __restrict__ dst,
    int K, int N, int bx, int by) {
  __shared__ float t[32][33];
  int n0 = bx * 32, k0 = by * 32;
  int tx = threadIdx.x & 31, ty = threadIdx.x >> 5;
  for (int i = 0; i < 4; ++i) {
    int ky = ty + i * 8;
    t[ky][tx] = src[(size_t)(k0 + ky) * N + n0 + tx];
  }
  __syncthreads();
  for (int i = 0; i < 4; ++i) {
    int ny = ty + i * 8;
    dst[(size_t)(n0 + ny) * K + k0 + tx] = __float2bfloat16(t[tx][ny]);
  }
}

__global__ __launch_bounds__(256) void prep_kernel(
    const float* __restrict__ msa, const unsigned char* __restrict__ mraw,
    const float* __restrict__ w_qkv, const float* __restrict__ w_out,
    __hip_bfloat16* __restrict__ msa_c, float* __restrict__ mout,
    __hip_bfloat16* __restrict__ wqkv_t, __hip_bfloat16* __restrict__ wout_t) {
  int b = blockIdx.x;
  int tid = threadIdx.x;
  if (b < 1024) {
    // fp32 -> bf16 bulk convert (stride hardcoded for 1024 virtual blocks)
    for (int i = (b * 256 + tid) * 4; i < NN * LL * DD; i += 1024 * 1024) {
      float4 v = *(const float4*)(msa + i);
      ushort4 o;
      o.x = __bfloat16_as_ushort(__float2bfloat16(v.x));
      o.y = __bfloat16_as_ushort(__float2bfloat16(v.y));
      o.z = __bfloat16_as_ushort(__float2bfloat16(v.z));
      o.w = __bfloat16_as_ushort(__float2bfloat16(v.w));
      *(ushort4*)(msa_c + i) = o;
    }
  } else if (b < 1056) {
    // mask normalization -> float 1.0/0.0 at k'-PERMUTED index
    __shared__ int s_or1, s_or2, s_or3, s_max, s_mode;
    if (tid == 0) { s_or1 = 0; s_or2 = 0; s_or3 = 0; s_max = 0; }
    __syncthreads();
    int or1 = 0, or2 = 0, or3 = 0, mx = 0;
    for (int j = tid; j < 4096; j += 256) {
      int v = mraw[j];
      mx = mx > v ? mx : v;
      int r = j & 3;
      if (r == 1) or1 |= v;
      else if (r == 2) or2 |= v;
      else if (r == 3) or3 |= v;
    }
    atomicOr(&s_or1, or1); atomicOr(&s_or2, or2); atomicOr(&s_or3, or3);
    atomicMax(&s_max, mx);
    __syncthreads();
    if (tid == 0) {
      int mode;
      if (s_max <= 1) mode = ((s_or1 | s_or2 | s_or3) == 0) ? MODE_I32 : MODE_I8;
      else            mode = (s_or1 != 0) ? MODE_BF16 : MODE_F32;
      s_mode = mode;
    }
    __syncthreads();
    int mode = s_mode;
    int i0 = (b - 1024) * 1024;
    for (int i = i0 + tid; i < i0 + 1024; i += 256) {
      int v;
      if (mode == MODE_I32)       v = ((const int*)mraw)[i] != 0;
      else if (mode == MODE_I8)   v = mraw[i] != 0;
      else if (mode == MODE_BF16) v = ((const unsigned short*)mraw)[i] != 0;
      else                        v = ((const unsigned int*)mraw)[i] != 0;
      mout[(i & ~255) | permk(i & 255)] = v ? 1.f : 0.f;
    }
  } else if (b < 1248) {
    int bb = b - 1056;
    transpose_cvt_body(w_qkv, wqkv_t, 256, 768, bb % 24, bb / 24);
  } else {
    int bb = b - 1248;
    transpose_cvt_body(w_out, wout_t, 256, 256, bb % 8, bb / 8);
  }
}

// ---------------------------------------------------------------------------
// MFMA GEMM pipeline (A [M][256] bf16, Bt [N][256] bf16 = B^T).
// 128x128 tile, BK=32, 4 waves of 64x64, SWAPPED mfma (C^T fragments: lane
// holds 4 consecutive gcol at one grow -> wide coalesced stores).
// 2-phase LDS double-buffer; XOR-swizzle via pre-swizzled global source.
// Aptr/Btptr are real locals (macro-scope; GSTAGE expands on rescan).
// ---------------------------------------------------------------------------
#define GSTAGE(AD, BD, KS)                                                    \
  {                                                                           \
    const int k0_ = (KS) * 32;                                                \
    gload_lds16(Aptr + ((size_t)(bm * 128 + srow)) * 256 + k0_ + scc * 8,     \
                AD + (size_t)(wv * 64) * 8);                                  \
    gload_lds16(Btptr + ((size_t)(bn * 128 + srow)) * 256 + k0_ + scc * 8,    \
                BD + (size_t)(wv * 64) * 8);                                  \
    gload_lds16(Aptr + ((size_t)(bm * 128 + 64 + srow)) * 256 + k0_ + scc * 8,\
                AD + (size_t)(wv * 64 + 256) * 8);                            \
    gload_lds16(Btptr + ((size_t)(bn * 128 + 64 + srow)) * 256 + k0_ + scc * 8,\
                BD + (size_t)(wv * 64 + 256) * 8);                            \
  }

#define GPHASE(CA, CB, NA, NB, NKS, DOSTAGE)                                  \
  {                                                                           \
    if (DOSTAGE) GSTAGE(NA, NB, NKS)                                          \
    bf16x8 af[4], bfr[4];                                                     \
    _Pragma("unroll") for (int mi = 0; mi < 4; ++mi) {                        \
      int r_ = wm + mi * 16 + lr;                                             \
      af[mi] = *(const bf16x8*)&CA[r_ * 32 + (quad ^ (r_ & 3)) * 8];          \
    }                                                                         \
    _Pragma("unroll") for (int ni = 0; ni < 4; ++ni) {                        \
      int r_ = wn + ni * 16 + lr;                                             \
      bfr[ni] = *(const bf16x8*)&CB[r_ * 32 + (quad ^ (r_ & 3)) * 8];         \
    }                                                                         \
    _Pragma("unroll") for (int mi = 0; mi < 4; ++mi)                          \
      _Pragma("unroll") for (int ni = 0; ni < 4; ++ni)                        \
        acc[mi][ni] = __builtin_amdgcn_mfma_f32_16x16x32_bf16(                \
            bfr[ni], af[mi], acc[mi][ni], 0, 0, 0);                           \
  }                                                                           \
  __syncthreads();

#define GEMM_PIPELINE(APTR_, BTPTR_, BM_, BN_)                                \
  const __hip_bfloat16* __restrict__ Aptr = (APTR_);                          \
  const __hip_bfloat16* __restrict__ Btptr = (BTPTR_);                        \
  int lane = tid & 63, wv = tid >> 6;                                         \
  int wm = (wv >> 1) * 64, wn = (wv & 1) * 64;                                \
  int lr = lane & 15, quad = lane >> 4;                                       \
  int bm = (BM_), bn = (BN_);                                                 \
  int srow = tid >> 2, sslot = tid & 3;                                       \
  int scc = sslot ^ (srow & 3);                                               \
  f32x4 acc[4][4];                                                            \
  for (int i = 0; i < 4; ++i)                                                 \
    for (int j = 0; j < 4; ++j) acc[i][j] = (f32x4){0.f, 0.f, 0.f, 0.f};      \
  GSTAGE(As0, Bs0, 0)                                                         \
  __syncthreads();                                                            \
  GPHASE(As0, Bs0, As1, Bs1, 1, 1)                                            \
  GPHASE(As1, Bs1, As0, Bs0, 2, 1)                                            \
  GPHASE(As0, Bs0, As1, Bs1, 3, 1)                                            \
  GPHASE(As1, Bs1, As0, Bs0, 4, 1)                                            \
  GPHASE(As0, Bs0, As1, Bs1, 5, 1)                                            \
  GPHASE(As1, Bs1, As0, Bs0, 6, 1)                                            \
  GPHASE(As0, Bs0, As1, Bs1, 7, 1)                                            \
  GPHASE(As1, Bs1, As0, Bs0, 8, 0)

// ---------------------------------------------------------------------------
// FUSED qkv_gemm + pair_bias (independent work, disjoint block ranges;
// one launch instead of two -> one less gap, pair rides in qkv's shadow).
// Blocks [0,1536): qkv GEMM (bm = b&255, bn = b>>8).
// Blocks [1536,3584): pair_bias (row0 = (b-1536)*32).
// Static LDS = 32K (GEMM dbuf) + 21K (pair) = 54K < 64K workgroup cap.
// ---------------------------------------------------------------------------
__global__ __launch_bounds__(256) void qkv_pair_fused(
    const __hip_bfloat16* __restrict__ A,
    const __hip_bfloat16* __restrict__ Bt,
    __hip_bfloat16* __restrict__ qb,
    __hip_bfloat16* __restrict__ kb,
    __hip_bfloat16* __restrict__ vb,
    const float* __restrict__ pair,
    const float* __restrict__ w_pb,
    const float* __restrict__ b_pb,
    __hip_bfloat16* __restrict__ expb) {
  __shared__ __align__(16) __hip_bfloat16 As0[128 * 32], As1[128 * 32];
  __shared__ __align__(16) __hip_bfloat16 Bs0[128 * 32], Bs1[128 * 32];
  __shared__ float wp[128][9];
  __shared__ float rows[32][129];
  int b = blockIdx.x;
  int tid = threadIdx.x;
  if (b < 1536) {
    // ---- qkv GEMM: q,k -> [n][h][l][dh]; v -> [n][h][dh][l'] ----
    GEMM_PIPELINE(A, Bt, b & 255, b >> 8)
    int t = bn >> 1;
#pragma unroll
    for (int mi = 0; mi < 4; ++mi) {
      int g = bm * 128 + wm + mi * 16 + lr;
      int n = g >> 8, l = g & 255;
      int lp = permk(l);
#pragma unroll
      for (int ni = 0; ni < 4; ++ni) {
        int rem = (bn * 128 + wn + ni * 16 + quad * 4) & 255;
        int h = rem >> 5, dh0 = rem & 31;
        if (t < 2) {
          ushort4 w;
          w.x = __bfloat16_as_ushort(__float2bfloat16(acc[mi][ni][0]));
          w.y = __bfloat16_as_ushort(__float2bfloat16(acc[mi][ni][1]));
          w.z = __bfloat16_as_ushort(__float2bfloat16(acc[mi][ni][2]));
          w.w = __bfloat16_as_ushort(__float2bfloat16(acc[mi][ni][3]));
          __hip_bfloat16* dst = (t == 0 ? qb : kb);
          *(ushort4*)(dst + ((size_t)((n * HH + h) * LL + l)) * DHH + dh0) = w;
        } else {
#pragma unroll
          for (int r = 0; r < 4; ++r)
            vb[((size_t)((n * HH + h) * DHH + dh0 + r)) * LL + lp] =
                __float2bfloat16(acc[mi][ni][r]);
        }
      }
    }
  } else {
    // ---- pair bias -> expb[h][q][k'] = exp(pair@w_pb + b_pb - 12) bf16 ----
    for (int i = 0; i < 4; ++i) {
      int e = tid + i * 256;
      wp[e >> 3][e & 7] = w_pb[e];
    }
    int row0 = (b - 1536) * 32;
    const float* src = pair + (size_t)row0 * PP;
    for (int i = 0; i < 16; ++i) {
      int e = tid + i * 256;
      int r = e >> 7, c = e & 127;
      rows[r][c] = src[r * 128 + c];
    }
    __syncthreads();
    int h = tid >> 5, rl = tid & 31;
    float acc = b_pb[h] - 12.0f;
    for (int p = 0; p < 128; ++p)
      acc += rows[rl][p] * wp[p][h];
    int row = row0 + rl;
    int i = row >> 8, j = row & 255;
    expb[((size_t)(h * LL + i)) * LL + permk(j)] = __float2bfloat16(__expf(acc));
  }
}

__global__ __launch_bounds__(256) void out_gemm_mfma(
    const __hip_bfloat16* __restrict__ A,
    const __hip_bfloat16* __restrict__ Bt,
    const float* __restrict__ bout,
    float* __restrict__ C) {
  __shared__ __align__(16) __hip_bfloat16 As0[128 * 32], As1[128 * 32];
  __shared__ __align__(16) __hip_bfloat16 Bs0[128 * 32], Bs1[128 * 32];
  int tid = threadIdx.x;
  GEMM_PIPELINE(A, Bt, blockIdx.x, blockIdx.y)
#pragma unroll
  for (int mi = 0; mi < 4; ++mi) {
    int g = bm * 128 + wm + mi * 16 + lr;
#pragma unroll
    for (int ni = 0; ni < 4; ++ni) {
      int gcol0 = bn * 128 + wn + ni * 16 + quad * 4;
      float4 bo = *(const float4*)(bout + gcol0);
      float4 v;
      v.x = acc[mi][ni][0] + bo.x;
      v.y = acc[mi][ni][1] + bo.y;
      v.z = acc[mi][ni][2] + bo.z;
      v.w = acc[mi][ni][3] + bo.w;
      *(float4*)(C + (size_t)g * 256 + gcol0) = v;
    }
  }
}

// ---------------------------------------------------------------------------
// Flash-style MFMA attention (round-6 version, VERBATIM revert of round 7:
// the VALU->MFMA/producer offload dropped VGPR 128->84 = compiler sank the
// K/V prefetch loads, collapsing the pipeline; 46.7 -> 70.5us. The VALU ops
// between load issue and consume are load-hiding ballast — keep them).
// Zero LDS, swapped QK^T, fixed-shift softmax, pre-exponentiated bf16 bias,
// k'-permuted layouts, per-kt issue order [eb, mask, K/V(kt+1)].
// ---------------------------------------------------------------------------
__global__ __launch_bounds__(256, 2) void attn_mfma(
    const __hip_bfloat16* __restrict__ qb,
    const __hip_bfloat16* __restrict__ kb,
    const __hip_bfloat16* __restrict__ vbt,   // [n][h][dh][k'] bf16
    const __hip_bfloat16* __restrict__ expb,  // [h][q][k'] = exp(bias-12) bf16
    const float* __restrict__ maskf,          // [n][k'] 1.0/0.0
    __hip_bfloat16* __restrict__ ao) {
  int bx = blockIdx.x;
  int h = bx >> 7, n = bx & 127;
  int nh = n * HH + h;
  int tid = threadIdx.x, lane = tid & 63, wv = tid >> 6;
  int lr = lane & 15, quad = lane >> 4;
  int wm = wv * 64;
  size_t base = (size_t)nh * (LL * DHH);

  const __hip_bfloat16* qp = qb + base;
  const __hip_bfloat16* kp = kb + base;
  const __hip_bfloat16* vp = vbt + base;
  const __hip_bfloat16* ep = expb + (size_t)h * LL * LL;
  const float* mrow = maskf + n * LL;

  const float cs = 0.17677669529663687f * 1.4426950408889634f;  // scale*log2e

  // Q fragments (row q = wm+mi*16+lr, dh = quad*8..+7); B-operand of QK^T.
  bf16x8 aq[4];
#pragma unroll
  for (int mi = 0; mi < 4; ++mi)
    aq[mi] = *(const bf16x8*)(qp + (size_t)(wm + mi * 16 + lr) * DHH + quad * 8);

  // K double-buffered (A/B tokens); V likewise (contig 16B halves a/b per no).
  bf16x8 bkA[4], bkB[4];
  s16x8 avA0a, avA0b, avA1a, avA1b;
  s16x8 avB0a, avB0b, avB1a, avB1b;
  // eb: all 4 mi of the CURRENT kt, single-buffered (2x16B per mi).
  uint4 e0a, e0b, e1a, e1b, e2a, e2b, e3a, e3b;
  // mask multipliers for current kt (k'-contiguous).
  f32x4 mw0, mw1, mw2, mw3;

#define LOADKT(S, KT)                                                          \
  {                                                                            \
    const int j0_ = (KT) * 64;                                                 \
    _Pragma("unroll") for (int nj = 0; nj < 4; ++nj)                           \
        bk##S[nj] =                                                            \
        *(const bf16x8*)(kp + (size_t)(j0_ + nj * 16 + lr) * DHH + quad * 8);  \
    av##S##0a = *(const s16x8*)(vp + (size_t)lr * LL + j0_ + quad * 16);       \
    av##S##0b = *(const s16x8*)(vp + (size_t)lr * LL + j0_ + quad * 16 + 8);   \
    av##S##1a = *(const s16x8*)(vp + (size_t)(16 + lr) * LL + j0_ + quad * 16);\
    av##S##1b =                                                                \
        *(const s16x8*)(vp + (size_t)(16 + lr) * LL + j0_ + quad * 16 + 8);    \
  }

#define LOADEB_ALL(KT)                                                         \
  {                                                                            \
    const int j0_ = (KT) * 64;                                                 \
    e0a = *(const uint4*)(ep + (size_t)(wm + 0 + lr) * LL + j0_ + quad * 16);  \
    e0b = *(const uint4*)(ep + (size_t)(wm + 0 + lr) * LL + j0_ + quad * 16 + 8);\
    e1a = *(const uint4*)(ep + (size_t)(wm + 16 + lr) * LL + j0_ + quad * 16); \
    e1b = *(const uint4*)(ep + (size_t)(wm + 16 + lr) * LL + j0_ + quad * 16 + 8);\
    e2a = *(const uint4*)(ep + (size_t)(wm + 32 + lr) * LL + j0_ + quad * 16); \
    e2b = *(const uint4*)(ep + (size_t)(wm + 32 + lr) * LL + j0_ + quad * 16 + 8);\
    e3a = *(const uint4*)(ep + (size_t)(wm + 48 + lr) * LL + j0_ + quad * 16); \
    e3b = *(const uint4*)(ep + (size_t)(wm + 48 + lr) * LL + j0_ + quad * 16 + 8);\
  }

#define LOADMW(KT)                                                             \
  {                                                                            \
    const int j0_ = (KT) * 64;                                                 \
    mw0 = *(const f32x4*)(mrow + j0_ + quad * 16 + 0);                         \
    mw1 = *(const f32x4*)(mrow + j0_ + quad * 16 + 4);                         \
    mw2 = *(const f32x4*)(mrow + j0_ + quad * 16 + 8);                         \
    mw3 = *(const f32x4*)(mrow + j0_ + quad * 16 + 12);                        \
  }

// One nj step of one (kt,mi) phase. EX/EY = the two eb dwords for this nj,
// AV0/AV1 = 16B V fragments (no=0,1), LO = element offset (0 or 4).
#define NJ_STEP(C, MI, NJ, EX, EY, AV0, AV1, LO)                               \
  {                                                                            \
    f32x4 s_ = __builtin_amdgcn_mfma_f32_16x16x32_bf16(                        \
        bk##C[NJ], aq[MI], (f32x4){0.f, 0.f, 0.f, 0.f}, 0, 0, 0);              \
    float em0_ = __uint_as_float((EX) << 16) * mw##NJ[0];                      \
    float em1_ = __uint_as_float((EX) & 0xffff0000u) * mw##NJ[1];              \
    float em2_ = __uint_as_float((EY) << 16) * mw##NJ[2];                      \
    float em3_ = __uint_as_float((EY) & 0xffff0000u) * mw##NJ[3];              \
    float p0_ = exp2f(s_[0] * cs) * em0_;                                      \
    float p1_ = exp2f(s_[1] * cs) * em1_;                                      \
    float p2_ = exp2f(s_[2] * cs) * em2_;                                      \
    float p3_ = exp2f(s_[3] * cs) * em3_;                                      \
    lsum[MI] += (p0_ + p1_) + (p2_ + p3_);                                     \
    unsigned lo_ =                                                             \
        ((unsigned)__bfloat16_as_ushort(__float2bfloat16(p1_)) << 16) |        \
        (unsigned)__bfloat16_as_ushort(__float2bfloat16(p0_));                 \
    unsigned hi_ =                                                             \
        ((unsigned)__bfloat16_as_ushort(__float2bfloat16(p3_)) << 16) |        \
        (unsigned)__bfloat16_as_ushort(__float2bfloat16(p2_));                 \
    u32x2 pu_ = {lo_, hi_};                                                    \
    s16x4 pb_ = __builtin_bit_cast(s16x4, pu_);                                \
    s16x4 a0_ = __builtin_shufflevector(AV0, AV0, LO, LO + 1, LO + 2, LO + 3); \
    s16x4 a1_ = __builtin_shufflevector(AV1, AV1, LO, LO + 1, LO + 2, LO + 3); \
    o_acc[MI][0] = __builtin_amdgcn_mfma_f32_16x16x16bf16_1k(                  \
        a0_, pb_, o_acc[MI][0], 0, 0, 0);                                      \
    o_acc[MI][1] = __builtin_amdgcn_mfma_f32_16x16x16bf16_1k(                  \
        a1_, pb_, o_acc[MI][1], 0, 0, 0);                                      \
  }

#define MI_PHASE(MI, C, EA, EB_)                                               \
  {                                                                            \
    NJ_STEP(C, MI, 0, EA.x, EA.y, av##C##0a, av##C##1a, 0)                     \
    NJ_STEP(C, MI, 1, EA.z, EA.w, av##C##0a, av##C##1a, 4)                     \
    NJ_STEP(C, MI, 2, EB_.x, EB_.y, av##C##0b, av##C##1b, 0)                   \
    NJ_STEP(C, MI, 3, EB_.z, EB_.w, av##C##0b, av##C##1b, 4)                   \
  }

// Issue order per kt: eb (needed in ~1 phase, L2) first, then mask, then the
// NEXT kt's K/V (HBM, consumed a full kt later). Consumption is strictly in
// issue order -> compiler's counted vmcnt never drains fresh HBM loads.
#define KT_PHASE(KT, C, N, LAST)                                               \
  {                                                                            \
    LOADEB_ALL(KT)                                                             \
    LOADMW(KT)                                                                 \
    if (!(LAST)) LOADKT(N, (KT) + 1)                                           \
    MI_PHASE(0, C, e0a, e0b)                                                   \
    MI_PHASE(1, C, e1a, e1b)                                                   \
    MI_PHASE(2, C, e2a, e2b)                                                   \
    MI_PHASE(3, C, e3a, e3b)                                                   \
  }

  float lsum[4] = {0.f, 0.f, 0.f, 0.f};
  f32x4 o_acc[4][2];
#pragma unroll
  for (int mi = 0; mi < 4; ++mi)
#pragma unroll
    for (int no = 0; no < 2; ++no) o_acc[mi][no] = (f32x4){0.f, 0.f, 0.f, 0.f};

  LOADKT(A, 0)

  KT_PHASE(0, A, B, 0)
  KT_PHASE(1, B, A, 0)
  KT_PHASE(2, A, B, 0)
  KT_PHASE(3, B, A, 1)

#undef LOADKT
#undef LOADEB_ALL
#undef LOADMW
#undef NJ_STEP
#undef MI_PHASE
#undef KT_PHASE

  // epilogue: O^T tile (row dh = no*16+quad*4+r, col q = wm+mi*16+lr).
#pragma unroll
  for (int mi = 0; mi < 4; ++mi) {
    float ls = lsum[mi];
    ls += __shfl_xor(ls, 16);
    ls += __shfl_xor(ls, 32);
    float inv = (ls > 0.f) ? 1.f / ls : 0.f;
    int q = wm + mi * 16 + lr;
#pragma unroll
    for (int no = 0; no < 2; ++no) {
      f32x4 o = o_acc[mi][no];
      ushort4 w;
      w.x = __bfloat16_as_ushort(__float2bfloat16(o[0] * inv));
      w.y = __bfloat16_as_ushort(__float2bfloat16(o[1] * inv));
      w.z = __bfloat16_as_ushort(__float2bfloat16(o[2] * inv));
      w.w = __bfloat16_as_ushort(__float2bfloat16(o[3] * inv));
      *(ushort4*)(ao + (size_t)n * (LL * DD) + (size_t)q * DD +
                  h * DHH + no * 16 + quad * 4) = w;
    }
  }
}

extern "C" void kernel_launch(void* const* d_in, const int* in_sizes, int n_in,
                              void* d_out, int out_size, void* d_ws, size_t ws_size,
                              hipStream_t stream) {
  const float* msa   = (const float*)d_in[0];
  const float* pair  = (const float*)d_in[1];
  const unsigned char* mask = (const unsigned char*)d_in[2];
  const float* w_qkv = (const float*)d_in[3];
  const float* w_pb  = (const float*)d_in[4];
  const float* b_pb  = (const float*)d_in[5];
  const float* w_out = (const float*)d_in[6];
  const float* b_out = (const float*)d_in[7];
  float* out = (float*)d_out;

  char* ws = (char*)d_ws;
  __hip_bfloat16* qb      = (__hip_bfloat16*)(ws);                 // 16 MB
  __hip_bfloat16* kb      = (__hip_bfloat16*)(ws + 16777216);      // 16 MB
  __hip_bfloat16* vb      = (__hip_bfloat16*)(ws + 33554432);      // 16 MB [n][h][dh][k']
  __hip_bfloat16* msa_c   = (__hip_bfloat16*)(ws + 50331648);      // 16 MB
  __hip_bfloat16* ao      = (__hip_bfloat16*)(ws + 50331648);      // alias (msa dead after qkv)
  __hip_bfloat16* expb    = (__hip_bfloat16*)(ws + 67108864);      // 1 MB [h][q][k'] bf16
  __hip_bfloat16* wqkv_t  = (__hip_bfloat16*)(ws + 71303168);      // 384 KB
  __hip_bfloat16* wout_t  = (__hip_bfloat16*)(ws + 71696384);      // 128 KB
  float*          msk     = (float*)(ws + 71827456);               // 128 KB [n][k']

  prep_kernel<<<1312, 256, 0, stream>>>(msa, mask, w_qkv, w_out,
                                        msa_c, msk, wqkv_t, wout_t);
  qkv_pair_fused<<<3584, 256, 0, stream>>>(msa_c, wqkv_t, qb, kb, vb,
                                           pair, w_pb, b_pb, expb);
  attn_mfma<<<1024, 256, 0, stream>>>(qb, kb, vb, expb, msk, ao);
  out_gemm_mfma<<<dim3(256, 2), 256, 0, stream>>>(ao, wout_t, b_out, out);
}

// Round 9
// 207.741 us; speedup vs baseline: 1.0993x; 1.0283x over previous
//
#include <hip/hip_runtime.h>
#include <hip/hip_bf16.h>

// Problem constants: B=1, N=128, L=256, D=256, P=128, H=8, DH=32
// Established: fp32 inputs, fp32 output; bf16-rounded ref, threshold 0.0289.
#define NN 128
#define LL 256
#define DD 256
#define PP 128
#define HH 8
#define DHH 32

typedef __bf16 bf16x8 __attribute__((ext_vector_type(8)));
typedef short s16x4 __attribute__((ext_vector_type(4)));
typedef short s16x8 __attribute__((ext_vector_type(8)));
typedef float f32x4 __attribute__((ext_vector_type(4)));
typedef unsigned int u32x2 __attribute__((ext_vector_type(2)));

// k' permutation: within each 64-block, swap bits[5:4] (nj) with bits[3:2]
// (quad) so that a lane's MFMA-fragment elements become CONTIGUOUS 16
// values. Self-inverse. Applied at the producers for expb, vb, msk.
__device__ __forceinline__ int permk(int k) {
  return (k & 0xC3) | ((k & 0x30) >> 2) | ((k & 0x0C) << 2);
}

// async global->LDS, 16B per lane (dest = wave-uniform base + lane*16)
__device__ __forceinline__ void gload_lds16(const void* g, void* l) {
  __builtin_amdgcn_global_load_lds(
      (const __attribute__((address_space(1))) void*)g,
      (__attribute__((address_space(3))) void*)l, 16, 0, 0);
}

// ---------------------------------------------------------------------------
// FUSED prep kernel. Block ranges: [0,1024) cvt msa->bf16; [1024,1056) mask
// normalize; [1056,1248) transpose w_qkv; [1248,1312) transpose w_out.
// ---------------------------------------------------------------------------
#define MODE_I32 0
#define MODE_I8 1
#define MODE_BF16 2
#define MODE_F32 3

__device__ __forceinline__ void transpose_cvt_body(
    const float* __restrict__ src, __hip_bfloat16* __restrict__ dst,
    int K, int N, int bx, int by) {
  __shared__ float t[32][33];
  int n0 = bx * 32, k0 = by * 32;
  int tx = threadIdx.x & 31, ty = threadIdx.x >> 5;
  for (int i = 0; i < 4; ++i) {
    int ky = ty + i * 8;
    t[ky][tx] = src[(size_t)(k0 + ky) * N + n0 + tx];
  }
  __syncthreads();
  for (int i = 0; i < 4; ++i) {
    int ny = ty + i * 8;
    dst[(size_t)(n0 + ny) * K + k0 + tx] = __float2bfloat16(t[tx][ny]);
  }
}

__global__ __launch_bounds__(256) void prep_kernel(
    const float* __restrict__ msa, const unsigned char* __restrict__ mraw,
    const float* __restrict__ w_qkv, const float* __restrict__ w_out,
    __hip_bfloat16* __restrict__ msa_c, float* __restrict__ mout,
    __hip_bfloat16* __restrict__ wqkv_t, __hip_bfloat16* __restrict__ wout_t) {
  int b = blockIdx.x;
  int tid = threadIdx.x;
  if (b < 1024) {
    for (int i = (b * 256 + tid) * 4; i < NN * LL * DD; i += 1024 * 1024) {
      float4 v = *(const float4*)(msa + i);
      ushort4 o;
      o.x = __bfloat16_as_ushort(__float2bfloat16(v.x));
      o.y = __bfloat16_as_ushort(__float2bfloat16(v.y));
      o.z = __bfloat16_as_ushort(__float2bfloat16(v.z));
      o.w = __bfloat16_as_ushort(__float2bfloat16(v.w));
      *(ushort4*)(msa_c + i) = o;
    }
  } else if (b < 1056) {
    __shared__ int s_or1, s_or2, s_or3, s_max, s_mode;
    if (tid == 0) { s_or1 = 0; s_or2 = 0; s_or3 = 0; s_max = 0; }
    __syncthreads();
    int or1 = 0, or2 = 0, or3 = 0, mx = 0;
    for (int j = tid; j < 4096; j += 256) {
      int v = mraw[j];
      mx = mx > v ? mx : v;
      int r = j & 3;
      if (r == 1) or1 |= v;
      else if (r == 2) or2 |= v;
      else if (r == 3) or3 |= v;
    }
    atomicOr(&s_or1, or1); atomicOr(&s_or2, or2); atomicOr(&s_or3, or3);
    atomicMax(&s_max, mx);
    __syncthreads();
    if (tid == 0) {
      int mode;
      if (s_max <= 1) mode = ((s_or1 | s_or2 | s_or3) == 0) ? MODE_I32 : MODE_I8;
      else            mode = (s_or1 != 0) ? MODE_BF16 : MODE_F32;
      s_mode = mode;
    }
    __syncthreads();
    int mode = s_mode;
    int i0 = (b - 1024) * 1024;
    for (int i = i0 + tid; i < i0 + 1024; i += 256) {
      int v;
      if (mode == MODE_I32)       v = ((const int*)mraw)[i] != 0;
      else if (mode == MODE_I8)   v = mraw[i] != 0;
      else if (mode == MODE_BF16) v = ((const unsigned short*)mraw)[i] != 0;
      else                        v = ((const unsigned int*)mraw)[i] != 0;
      mout[(i & ~255) | permk(i & 255)] = v ? 1.f : 0.f;
    }
  } else if (b < 1248) {
    int bb = b - 1056;
    transpose_cvt_body(w_qkv, wqkv_t, 256, 768, bb % 24, bb / 24);
  } else {
    int bb = b - 1248;
    transpose_cvt_body(w_out, wout_t, 256, 256, bb % 8, bb / 8);
  }
}

// ---------------------------------------------------------------------------
// MFMA GEMM pipeline (A [M][256] bf16, Bt [N][256] bf16 = B^T).
// 128x128 tile, BK=32, 4 waves of 64x64, SWAPPED mfma, 2-phase LDS dbuf.
// Round-9 swizzle fix: slot' = slot ^ ((row>>1)&3). Bank granule =
// 4*(row&1) + slot mod 8; old (row&3) XOR put lanes lr and lr+4 in the same
// granule (4-way). (row>>1)&3 makes granules distinct over row mod 8 ->
// 2 lanes/granule = conflict-free (m136: 2-way is free). Same involution on
// the pre-swizzled global source (GSTAGE) and the LDS read (GPHASE).
// ---------------------------------------------------------------------------
#define GSTAGE(AD, BD, KS)                                                    \
  {                                                                           \
    const int k0_ = (KS) * 32;                                                \
    gload_lds16(Aptr + ((size_t)(bm * 128 + srow)) * 256 + k0_ + scc * 8,     \
                AD + (size_t)(wv * 64) * 8);                                  \
    gload_lds16(Btptr + ((size_t)(bn * 128 + srow)) * 256 + k0_ + scc * 8,    \
                BD + (size_t)(wv * 64) * 8);                                  \
    gload_lds16(Aptr + ((size_t)(bm * 128 + 64 + srow)) * 256 + k0_ + scc * 8,\
                AD + (size_t)(wv * 64 + 256) * 8);                            \
    gload_lds16(Btptr + ((size_t)(bn * 128 + 64 + srow)) * 256 + k0_ + scc * 8,\
                BD + (size_t)(wv * 64 + 256) * 8);                            \
  }

#define GPHASE(CA, CB, NA, NB, NKS, DOSTAGE)                                  \
  {                                                                           \
    if (DOSTAGE) GSTAGE(NA, NB, NKS)                                          \
    bf16x8 af[4], bfr[4];                                                     \
    _Pragma("unroll") for (int mi = 0; mi < 4; ++mi) {                        \
      int r_ = wm + mi * 16 + lr;                                             \
      af[mi] = *(const bf16x8*)&CA[r_ * 32 + (quad ^ ((r_ >> 1) & 3)) * 8];   \
    }                                                                         \
    _Pragma("unroll") for (int ni = 0; ni < 4; ++ni) {                        \
      int r_ = wn + ni * 16 + lr;                                             \
      bfr[ni] = *(const bf16x8*)&CB[r_ * 32 + (quad ^ ((r_ >> 1) & 3)) * 8];  \
    }                                                                         \
    _Pragma("unroll") for (int mi = 0; mi < 4; ++mi)                          \
      _Pragma("unroll") for (int ni = 0; ni < 4; ++ni)                        \
        acc[mi][ni] = __builtin_amdgcn_mfma_f32_16x16x32_bf16(                \
            bfr[ni], af[mi], acc[mi][ni], 0, 0, 0);                           \
  }                                                                           \
  __syncthreads();

#define GEMM_PIPELINE(APTR_, BTPTR_, BM_, BN_)                                \
  const __hip_bfloat16* __restrict__ Aptr = (APTR_);                          \
  const __hip_bfloat16* __restrict__ Btptr = (BTPTR_);                        \
  int lane = tid & 63, wv = tid >> 6;                                         \
  int wm = (wv >> 1) * 64, wn = (wv & 1) * 64;                                \
  int lr = lane & 15, quad = lane >> 4;                                       \
  int bm = (BM_), bn = (BN_);                                                 \
  int srow = tid >> 2, sslot = tid & 3;                                       \
  int scc = sslot ^ ((srow >> 1) & 3);                                        \
  f32x4 acc[4][4];                                                            \
  for (int i = 0; i < 4; ++i)                                                 \
    for (int j = 0; j < 4; ++j) acc[i][j] = (f32x4){0.f, 0.f, 0.f, 0.f};      \
  GSTAGE(As0, Bs0, 0)                                                         \
  __syncthreads();                                                            \
  GPHASE(As0, Bs0, As1, Bs1, 1, 1)                                            \
  GPHASE(As1, Bs1, As0, Bs0, 2, 1)                                            \
  GPHASE(As0, Bs0, As1, Bs1, 3, 1)                                            \
  GPHASE(As1, Bs1, As0, Bs0, 4, 1)                                            \
  GPHASE(As0, Bs0, As1, Bs1, 5, 1)                                            \
  GPHASE(As1, Bs1, As0, Bs0, 6, 1)                                            \
  GPHASE(As0, Bs0, As1, Bs1, 7, 1)                                            \
  GPHASE(As1, Bs1, As0, Bs0, 8, 0)

// ---------------------------------------------------------------------------
// FUSED qkv_gemm + pair_bias. Round-9: LDS is a UNION (32KB), not a sum —
// round-8's 54KB (32K GEMM + 21K pair, disjoint block ranges!) cut GEMM
// occupancy 5 -> 3 blocks/CU (Occupancy 18%). One 32KB arena aliased by
// both sections restores 5 blocks/CU.
// Blocks [0,1536): qkv GEMM (bm = b&255, bn = b>>8).
// Blocks [1536,3584): pair_bias (row0 = (b-1536)*32).
// ---------------------------------------------------------------------------
__global__ __launch_bounds__(256) void qkv_pair_fused(
    const __hip_bfloat16* __restrict__ A,
    const __hip_bfloat16* __restrict__ Bt,
    __hip_bfloat16* __restrict__ qb,
    __hip_bfloat16* __restrict__ kb,
    __hip_bfloat16* __restrict__ vb,
    const float* __restrict__ pair,
    const float* __restrict__ w_pb,
    const float* __restrict__ b_pb,
    __hip_bfloat16* __restrict__ expb) {
  __shared__ __align__(16) unsigned char smem[32768];
  int b = blockIdx.x;
  int tid = threadIdx.x;
  if (b < 1536) {
    // ---- qkv GEMM: q,k -> [n][h][l][dh]; v -> [n][h][dh][l'] ----
    __hip_bfloat16* As0 = (__hip_bfloat16*)smem;
    __hip_bfloat16* As1 = (__hip_bfloat16*)(smem + 8192);
    __hip_bfloat16* Bs0 = (__hip_bfloat16*)(smem + 16384);
    __hip_bfloat16* Bs1 = (__hip_bfloat16*)(smem + 24576);
    GEMM_PIPELINE(A, Bt, b & 255, b >> 8)
    int t = bn >> 1;
#pragma unroll
    for (int mi = 0; mi < 4; ++mi) {
      int g = bm * 128 + wm + mi * 16 + lr;
      int n = g >> 8, l = g & 255;
      int lp = permk(l);
#pragma unroll
      for (int ni = 0; ni < 4; ++ni) {
        int rem = (bn * 128 + wn + ni * 16 + quad * 4) & 255;
        int h = rem >> 5, dh0 = rem & 31;
        if (t < 2) {
          ushort4 w;
          w.x = __bfloat16_as_ushort(__float2bfloat16(acc[mi][ni][0]));
          w.y = __bfloat16_as_ushort(__float2bfloat16(acc[mi][ni][1]));
          w.z = __bfloat16_as_ushort(__float2bfloat16(acc[mi][ni][2]));
          w.w = __bfloat16_as_ushort(__float2bfloat16(acc[mi][ni][3]));
          __hip_bfloat16* dst = (t == 0 ? qb : kb);
          *(ushort4*)(dst + ((size_t)((n * HH + h) * LL + l)) * DHH + dh0) = w;
        } else {
#pragma unroll
          for (int r = 0; r < 4; ++r)
            vb[((size_t)((n * HH + h) * DHH + dh0 + r)) * LL + lp] =
                __float2bfloat16(acc[mi][ni][r]);
        }
      }
    }
  } else {
    // ---- pair bias -> expb[h][q][k'] = exp(pair@w_pb + b_pb - 12) bf16 ----
    float (*wp)[9] = (float(*)[9])smem;               // 4608 B
    float (*rows)[129] = (float(*)[129])(smem + 4608);  // 16512 B (tot 21120)
    for (int i = 0; i < 4; ++i) {
      int e = tid + i * 256;
      wp[e >> 3][e & 7] = w_pb[e];
    }
    int row0 = (b - 1536) * 32;
    const float* src = pair + (size_t)row0 * PP;
    for (int i = 0; i < 16; ++i) {
      int e = tid + i * 256;
      int r = e >> 7, c = e & 127;
      rows[r][c] = src[r * 128 + c];
    }
    __syncthreads();
    int h = tid >> 5, rl = tid & 31;
    float acc = b_pb[h] - 12.0f;
    for (int p = 0; p < 128; ++p)
      acc += rows[rl][p] * wp[p][h];
    int row = row0 + rl;
    int i = row >> 8, j = row & 255;
    expb[((size_t)(h * LL + i)) * LL + permk(j)] = __float2bfloat16(__expf(acc));
  }
}

__global__ __launch_bounds__(256) void out_gemm_mfma(
    const __hip_bfloat16* __restrict__ A,
    const __hip_bfloat16* __restrict__ Bt,
    const float* __restrict__ bout,
    float* __restrict__ C) {
  __shared__ __align__(16) __hip_bfloat16 As0[128 * 32], As1[128 * 32];
  __shared__ __align__(16) __hip_bfloat16 Bs0[128 * 32], Bs1[128 * 32];
  int tid = threadIdx.x;
  GEMM_PIPELINE(A, Bt, blockIdx.x, blockIdx.y)
#pragma unroll
  for (int mi = 0; mi < 4; ++mi) {
    int g = bm * 128 + wm + mi * 16 + lr;
#pragma unroll
    for (int ni = 0; ni < 4; ++ni) {
      int gcol0 = bn * 128 + wn + ni * 16 + quad * 4;
      float4 bo = *(const float4*)(bout + gcol0);
      float4 v;
      v.x = acc[mi][ni][0] + bo.x;
      v.y = acc[mi][ni][1] + bo.y;
      v.z = acc[mi][ni][2] + bo.z;
      v.w = acc[mi][ni][3] + bo.w;
      *(float4*)(C + (size_t)g * 256 + gcol0) = v;
    }
  }
}

// ---------------------------------------------------------------------------
// Flash-style MFMA attention (round-6 version, kept verbatim: round-7 showed
// that trimming the VALU work between load issue and consume lets the
// scheduler sink the K/V prefetch (VGPR 128->84) and collapses the pipeline).
// Zero LDS, swapped QK^T, fixed-shift softmax, pre-exponentiated bf16 bias,
// k'-permuted layouts, per-kt issue order [eb, mask, K/V(kt+1)].
// ---------------------------------------------------------------------------
__global__ __launch_bounds__(256, 2) void attn_mfma(
    const __hip_bfloat16* __restrict__ qb,
    const __hip_bfloat16* __restrict__ kb,
    const __hip_bfloat16* __restrict__ vbt,   // [n][h][dh][k'] bf16
    const __hip_bfloat16* __restrict__ expb,  // [h][q][k'] = exp(bias-12) bf16
    const float* __restrict__ maskf,          // [n][k'] 1.0/0.0
    __hip_bfloat16* __restrict__ ao) {
  int bx = blockIdx.x;
  int h = bx >> 7, n = bx & 127;
  int nh = n * HH + h;
  int tid = threadIdx.x, lane = tid & 63, wv = tid >> 6;
  int lr = lane & 15, quad = lane >> 4;
  int wm = wv * 64;
  size_t base = (size_t)nh * (LL * DHH);

  const __hip_bfloat16* qp = qb + base;
  const __hip_bfloat16* kp = kb + base;
  const __hip_bfloat16* vp = vbt + base;
  const __hip_bfloat16* ep = expb + (size_t)h * LL * LL;
  const float* mrow = maskf + n * LL;

  const float cs = 0.17677669529663687f * 1.4426950408889634f;  // scale*log2e

  bf16x8 aq[4];
#pragma unroll
  for (int mi = 0; mi < 4; ++mi)
    aq[mi] = *(const bf16x8*)(qp + (size_t)(wm + mi * 16 + lr) * DHH + quad * 8);

  bf16x8 bkA[4], bkB[4];
  s16x8 avA0a, avA0b, avA1a, avA1b;
  s16x8 avB0a, avB0b, avB1a, avB1b;
  uint4 e0a, e0b, e1a, e1b, e2a, e2b, e3a, e3b;
  f32x4 mw0, mw1, mw2, mw3;

#define LOADKT(S, KT)                                                          \
  {                                                                            \
    const int j0_ = (KT) * 64;                                                 \
    _Pragma("unroll") for (int nj = 0; nj < 4; ++nj)                           \
        bk##S[nj] =                                                            \
        *(const bf16x8*)(kp + (size_t)(j0_ + nj * 16 + lr) * DHH + quad * 8);  \
    av##S##0a = *(const s16x8*)(vp + (size_t)lr * LL + j0_ + quad * 16);       \
    av##S##0b = *(const s16x8*)(vp + (size_t)lr * LL + j0_ + quad * 16 + 8);   \
    av##S##1a = *(const s16x8*)(vp + (size_t)(16 + lr) * LL + j0_ + quad * 16);\
    av##S##1b =                                                                \
        *(const s16x8*)(vp + (size_t)(16 + lr) * LL + j0_ + quad * 16 + 8);    \
  }

#define LOADEB_ALL(KT)                                                         \
  {                                                                            \
    const int j0_ = (KT) * 64;                                                 \
    e0a = *(const uint4*)(ep + (size_t)(wm + 0 + lr) * LL + j0_ + quad * 16);  \
    e0b = *(const uint4*)(ep + (size_t)(wm + 0 + lr) * LL + j0_ + quad * 16 + 8);\
    e1a = *(const uint4*)(ep + (size_t)(wm + 16 + lr) * LL + j0_ + quad * 16); \
    e1b = *(const uint4*)(ep + (size_t)(wm + 16 + lr) * LL + j0_ + quad * 16 + 8);\
    e2a = *(const uint4*)(ep + (size_t)(wm + 32 + lr) * LL + j0_ + quad * 16); \
    e2b = *(const uint4*)(ep + (size_t)(wm + 32 + lr) * LL + j0_ + quad * 16 + 8);\
    e3a = *(const uint4*)(ep + (size_t)(wm + 48 + lr) * LL + j0_ + quad * 16); \
    e3b = *(const uint4*)(ep + (size_t)(wm + 48 + lr) * LL + j0_ + quad * 16 + 8);\
  }

#define LOADMW(KT)                                                             \
  {                                                                            \
    const int j0_ = (KT) * 64;                                                 \
    mw0 = *(const f32x4*)(mrow + j0_ + quad * 16 + 0);                         \
    mw1 = *(const f32x4*)(mrow + j0_ + quad * 16 + 4);                         \
    mw2 = *(const f32x4*)(mrow + j0_ + quad * 16 + 8);                         \
    mw3 = *(const f32x4*)(mrow + j0_ + quad * 16 + 12);                        \
  }

#define NJ_STEP(C, MI, NJ, EX, EY, AV0, AV1, LO)                               \
  {                                                                            \
    f32x4 s_ = __builtin_amdgcn_mfma_f32_16x16x32_bf16(                        \
        bk##C[NJ], aq[MI], (f32x4){0.f, 0.f, 0.f, 0.f}, 0, 0, 0);              \
    float em0_ = __uint_as_float((EX) << 16) * mw##NJ[0];                      \
    float em1_ = __uint_as_float((EX) & 0xffff0000u) * mw##NJ[1];              \
    float em2_ = __uint_as_float((EY) << 16) * mw##NJ[2];                      \
    float em3_ = __uint_as_float((EY) & 0xffff0000u) * mw##NJ[3];              \
    float p0_ = exp2f(s_[0] * cs) * em0_;                                      \
    float p1_ = exp2f(s_[1] * cs) * em1_;                                      \
    float p2_ = exp2f(s_[2] * cs) * em2_;                                      \
    float p3_ = exp2f(s_[3] * cs) * em3_;                                      \
    lsum[MI] += (p0_ + p1_) + (p2_ + p3_);                                     \
    unsigned lo_ =                                                             \
        ((unsigned)__bfloat16_as_ushort(__float2bfloat16(p1_)) << 16) |        \
        (unsigned)__bfloat16_as_ushort(__float2bfloat16(p0_));                 \
    unsigned hi_ =                                                             \
        ((unsigned)__bfloat16_as_ushort(__float2bfloat16(p3_)) << 16) |        \
        (unsigned)__bfloat16_as_ushort(__float2bfloat16(p2_));                 \
    u32x2 pu_ = {lo_, hi_};                                                    \
    s16x4 pb_ = __builtin_bit_cast(s16x4, pu_);                                \
    s16x4 a0_ = __builtin_shufflevector(AV0, AV0, LO, LO + 1, LO + 2, LO + 3); \
    s16x4 a1_ = __builtin_shufflevector(AV1, AV1, LO, LO + 1, LO + 2, LO + 3); \
    o_acc[MI][0] = __builtin_amdgcn_mfma_f32_16x16x16bf16_1k(                  \
        a0_, pb_, o_acc[MI][0], 0, 0, 0);                                      \
    o_acc[MI][1] = __builtin_amdgcn_mfma_f32_16x16x16bf16_1k(                  \
        a1_, pb_, o_acc[MI][1], 0, 0, 0);                                      \
  }

#define MI_PHASE(MI, C, EA, EB_)                                               \
  {                                                                            \
    NJ_STEP(C, MI, 0, EA.x, EA.y, av##C##0a, av##C##1a, 0)                     \
    NJ_STEP(C, MI, 1, EA.z, EA.w, av##C##0a, av##C##1a, 4)                     \
    NJ_STEP(C, MI, 2, EB_.x, EB_.y, av##C##0b, av##C##1b, 0)                   \
    NJ_STEP(C, MI, 3, EB_.z, EB_.w, av##C##0b, av##C##1b, 4)                   \
  }

#define KT_PHASE(KT, C, N, LAST)                                               \
  {                                                                            \
    LOADEB_ALL(KT)                                                             \
    LOADMW(KT)                                                                 \
    if (!(LAST)) LOADKT(N, (KT) + 1)                                           \
    MI_PHASE(0, C, e0a, e0b)                                                   \
    MI_PHASE(1, C, e1a, e1b)                                                   \
    MI_PHASE(2, C, e2a, e2b)                                                   \
    MI_PHASE(3, C, e3a, e3b)                                                   \
  }

  float lsum[4] = {0.f, 0.f, 0.f, 0.f};
  f32x4 o_acc[4][2];
#pragma unroll
  for (int mi = 0; mi < 4; ++mi)
#pragma unroll
    for (int no = 0; no < 2; ++no) o_acc[mi][no] = (f32x4){0.f, 0.f, 0.f, 0.f};

  LOADKT(A, 0)

  KT_PHASE(0, A, B, 0)
  KT_PHASE(1, B, A, 0)
  KT_PHASE(2, A, B, 0)
  KT_PHASE(3, B, A, 1)

#undef LOADKT
#undef LOADEB_ALL
#undef LOADMW
#undef NJ_STEP
#undef MI_PHASE
#undef KT_PHASE

#pragma unroll
  for (int mi = 0; mi < 4; ++mi) {
    float ls = lsum[mi];
    ls += __shfl_xor(ls, 16);
    ls += __shfl_xor(ls, 32);
    float inv = (ls > 0.f) ? 1.f / ls : 0.f;
    int q = wm + mi * 16 + lr;
#pragma unroll
    for (int no = 0; no < 2; ++no) {
      f32x4 o = o_acc[mi][no];
      ushort4 w;
      w.x = __bfloat16_as_ushort(__float2bfloat16(o[0] * inv));
      w.y = __bfloat16_as_ushort(__float2bfloat16(o[1] * inv));
      w.z = __bfloat16_as_ushort(__float2bfloat16(o[2] * inv));
      w.w = __bfloat16_as_ushort(__float2bfloat16(o[3] * inv));
      *(ushort4*)(ao + (size_t)n * (LL * DD) + (size_t)q * DD +
                  h * DHH + no * 16 + quad * 4) = w;
    }
  }
}

extern "C" void kernel_launch(void* const* d_in, const int* in_sizes, int n_in,
                              void* d_out, int out_size, void* d_ws, size_t ws_size,
                              hipStream_t stream) {
  const float* msa   = (const float*)d_in[0];
  const float* pair  = (const float*)d_in[1];
  const unsigned char* mask = (const unsigned char*)d_in[2];
  const float* w_qkv = (const float*)d_in[3];
  const float* w_pb  = (const float*)d_in[4];
  const float* b_pb  = (const float*)d_in[5];
  const float* w_out = (const float*)d_in[6];
  const float* b_out = (const float*)d_in[7];
  float* out = (float*)d_out;

  char* ws = (char*)d_ws;
  __hip_bfloat16* qb      = (__hip_bfloat16*)(ws);                 // 16 MB
  __hip_bfloat16* kb      = (__hip_bfloat16*)(ws + 16777216);      // 16 MB
  __hip_bfloat16* vb      = (__hip_bfloat16*)(ws + 33554432);      // 16 MB [n][h][dh][k']
  __hip_bfloat16* msa_c   = (__hip_bfloat16*)(ws + 50331648);      // 16 MB
  __hip_bfloat16* ao      = (__hip_bfloat16*)(ws + 50331648);      // alias (msa dead after qkv)
  __hip_bfloat16* expb    = (__hip_bfloat16*)(ws + 67108864);      // 1 MB [h][q][k'] bf16
  __hip_bfloat16* wqkv_t  = (__hip_bfloat16*)(ws + 71303168);      // 384 KB
  __hip_bfloat16* wout_t  = (__hip_bfloat16*)(ws + 71696384);      // 128 KB
  float*          msk     = (float*)(ws + 71827456);               // 128 KB [n][k']

  prep_kernel<<<1312, 256, 0, stream>>>(msa, mask, w_qkv, w_out,
                                        msa_c, msk, wqkv_t, wout_t);
  qkv_pair_fused<<<3584, 256, 0, stream>>>(msa_c, wqkv_t, qb, kb, vb,
                                           pair, w_pb, b_pb, expb);
  attn_mfma<<<1024, 256, 0, stream>>>(qb, kb, vb, expb, msk, ao);
  out_gemm_mfma<<<dim3(256, 2), 256, 0, stream>>>(ao, wout_t, b_out, out);
}